// Round 13
// baseline (418.873 us; speedup 1.0000x reference)
//
#include <hip/hip_runtime.h>

#define H_ 448
#define CIN_ 128
#define HW_ (448*96)   // 43008
#define PPB 48

__device__ __forceinline__ float lrelu(float v){ return v > 0.0f ? v : 0.01f*v; }

// XCD-pairing decode for K1 half-line blocks.
__device__ __forceinline__ void decode_block(int d, int& h, int& par){
    const int r = d & 15, q = d >> 4;
    h   = (r & 7) + (q << 3);
    par = r >> 3;
}

// Counting sort of 96 pixels by class (NC classes). All threads must call.
template<int NC>
__device__ __forceinline__ void sort96(const unsigned char* s_cls, short* s_perm,
                                       int* s_cnt, int* s_off, int t)
{
    if (t < NC){
        int c = 0;
        for (int p = 0; p < 96; p++) if (s_cls[p] == (unsigned char)t) c++;
        s_cnt[t] = c;
    }
    __syncthreads();
    if (t == 0){
        int a = 0;
        for (int c = 0; c < NC; c++){ s_off[c] = a; a += s_cnt[c]; }
    }
    __syncthreads();
    if (t < NC){
        int o = s_off[t];
        for (int p = 0; p < 96; p++) if (s_cls[p] == (unsigned char)t) s_perm[o++] = (short)p;
    }
    __syncthreads();
}

// ================= K1: stage 1 (half-line blocks) — R10 verbatim =================
__global__ __launch_bounds__(384, 4)
void k1_stage1(const float* __restrict__ X,
               const float* __restrict__ w1_0, const float* __restrict__ b1_0,
               const float* __restrict__ w1_1, const float* __restrict__ b1_1,
               const float* __restrict__ w1_2, const float* __restrict__ b1_2,
               unsigned char* __restrict__ inds1)
{
    __shared__ float s_w0[4096];
    __shared__ float s_w1[1024];
    __shared__ float s_w2[256];
    __shared__ float s_A[PPB*33];
    __shared__ float s_B[PPB*33];

    int h, par; decode_block(blockIdx.x, h, par);
    const int wb = par * PPB;
    const int t  = threadIdx.x;
    const int w  = t % PPB;
    const int s  = t / PPB;
    const int hw = h*96 + wb + w;

    const float* g0 = w1_0 + (size_t)h*4096;
    for (int j = t; j < 4096; j += 384) s_w0[j] = g0[j];
    const float* g1 = w1_1 + (size_t)h*1024;
    for (int j = t; j < 1024; j += 384) s_w1[j] = g1[j];
    const float* g2 = w1_2 + (size_t)h*256;
    for (int j = t; j < 256; j += 384) s_w2[j] = g2[j];
    __syncthreads();

    {
        float acc[4];
        const float* bp = b1_0 + h*32 + s*4;
        #pragma unroll
        for (int k=0;k<4;k++) acc[k] = bp[k];
        #pragma unroll 4
        for (int i4=0;i4<32;i4++){
            const float x0 = X[(size_t)(4*i4+0)*HW_ + hw];
            const float x1 = X[(size_t)(4*i4+1)*HW_ + hw];
            const float x2 = X[(size_t)(4*i4+2)*HW_ + hw];
            const float x3 = X[(size_t)(4*i4+3)*HW_ + hw];
            #pragma unroll
            for (int k=0;k<4;k++){
                const float4 q = *(const float4*)&s_w0[(s*4+k)*128 + 4*i4];
                acc[k] += x0*q.x; acc[k] += x1*q.y; acc[k] += x2*q.z; acc[k] += x3*q.w;
            }
        }
        #pragma unroll
        for (int k=0;k<4;k++) s_A[w*33 + s*4 + k] = lrelu(acc[k]);
    }
    __syncthreads();

    {
        float acc[4];
        const float* bp = b1_1 + h*32 + s*4;
        #pragma unroll
        for (int k=0;k<4;k++) acc[k] = bp[k];
        #pragma unroll
        for (int i4=0;i4<8;i4++){
            const float x0 = s_A[w*33 + 4*i4+0];
            const float x1 = s_A[w*33 + 4*i4+1];
            const float x2 = s_A[w*33 + 4*i4+2];
            const float x3 = s_A[w*33 + 4*i4+3];
            #pragma unroll
            for (int k=0;k<4;k++){
                const float4 q = *(const float4*)&s_w1[(s*4+k)*32 + 4*i4];
                acc[k] += x0*q.x; acc[k] += x1*q.y; acc[k] += x2*q.z; acc[k] += x3*q.w;
            }
        }
        #pragma unroll
        for (int k=0;k<4;k++) s_B[w*33 + s*4 + k] = lrelu(acc[k]);
    }
    __syncthreads();

    {
        float acc = b1_2[h*8 + s];
        #pragma unroll
        for (int i4=0;i4<8;i4++){
            const float4 q = *(const float4*)&s_w2[s*32 + 4*i4];
            acc += s_B[w*33 + 4*i4+0]*q.x;
            acc += s_B[w*33 + 4*i4+1]*q.y;
            acc += s_B[w*33 + 4*i4+2]*q.z;
            acc += s_B[w*33 + 4*i4+3]*q.w;
        }
        s_A[w*33 + s] = acc;
    }
    __syncthreads();

    if (s == 0){
        const float* sc = &s_A[w*33];
        float best = sc[0]; int bi = 0;
        #pragma unroll
        for (int k=1;k<8;k++){ const float v = sc[k]; if (v > best){ best = v; bi = k; } }
        inds1[hw] = (unsigned char)bi;
    }
}

// ================= K2/K3: expert-wave, lane-per-pixel, scalar-broadcast weights ======
// One wave = one expert chunk (<=64 same-class pixels). Lane = one pixel; its 32
// activations live in registers. Weight pointers are wave-uniform (readfirstlane)
// -> s_load through the scalar pipe; no per-lane gather chains remain.
template<int NC, bool S3>
__global__ __launch_bounds__(512, 4)
void condmul_swave(const float* __restrict__ X,
                   const float* __restrict__ w0, const float* __restrict__ b0,
                   const float* __restrict__ w1, const float* __restrict__ b1,
                   const float* __restrict__ w2, const float* __restrict__ b2,
                   const unsigned char* __restrict__ route,
                   signed char* __restrict__ raw12,
                   unsigned char* __restrict__ cls2,
                   int* __restrict__ out)
{
    __shared__ unsigned char s_cls[96];
    __shared__ short s_perm[96];
    __shared__ int   s_cnt[NC];
    __shared__ int   s_off[NC];
    __shared__ int   s_chunk[72];    // (class<<16)|sorted_base, 64-px chunks
    __shared__ int   s_nch;

    const int h = blockIdx.x;
    const int t = threadIdx.x;
    if (t < 96) s_cls[t] = route[h*96 + t];
    __syncthreads();
    sort96<NC>(s_cls, s_perm, s_cnt, s_off, t);
    if (t == 0){
        int n = 0;
        for (int c = 0; c < NC; c++)
            for (int b = 0; b < s_cnt[c]; b += 64)
                s_chunk[n++] = (c << 16) | (s_off[c] + b);
        s_nch = n;
    }
    __syncthreads();

    const int wv   = t >> 6;      // wave 0..7
    const int lane = t & 63;
    const int nch  = s_nch;

    for (int ck = wv; ck < nch; ck += 8){
        const int info = __builtin_amdgcn_readfirstlane(s_chunk[ck]);
        const int c    = info >> 16;
        const int base = info & 0xffff;
        const int rend = __builtin_amdgcn_readfirstlane(s_off[c] + s_cnt[c]);
        const int m    = min(64, rend - base);
        const int li   = lane < m ? lane : m - 1;
        const int sp   = s_perm[base + li];
        const int hw   = h*96 + sp;
        const long e   = (long)h*NC + c;
        const float* W0e = w0 + e*4096;   // uniform -> scalar loads
        const float* W1e = w1 + e*1024;
        const float* W2e = w2 + e*512;

        // L0: 128 -> 32. Lane owns ALL 32 outputs; weights scalar-broadcast.
        float acc[32];
        {
            const float* bp = b0 + e*32;
            #pragma unroll
            for (int o=0;o<32;o++) acc[o] = bp[o];
        }
        #pragma unroll 4
        for (int i=0;i<128;i++){
            const float xv = X[(size_t)i*HW_ + hw];
            const float* wr = W0e + i*32;
            #pragma unroll
            for (int o=0;o<32;o++) acc[o] = fmaf(xv, wr[o], acc[o]);
        }
        #pragma unroll
        for (int o=0;o<32;o++) acc[o] = lrelu(acc[o]);

        // L1: 32 -> 32, fully unrolled (static indexing of acc[])
        float a2[32];
        {
            const float* bp = b1 + e*32;
            #pragma unroll
            for (int o=0;o<32;o++) a2[o] = bp[o];
        }
        #pragma unroll
        for (int i=0;i<32;i++){
            const float xv = acc[i];
            const float* wr = W1e + i*32;
            #pragma unroll
            for (int o=0;o<32;o++) a2[o] = fmaf(xv, wr[o], a2[o]);
        }
        #pragma unroll
        for (int o=0;o<32;o++) a2[o] = lrelu(a2[o]);

        // L2: 32 -> 16, fully unrolled
        float sc[16];
        {
            const float* bp = b2 + e*16;
            #pragma unroll
            for (int o=0;o<16;o++) sc[o] = bp[o];
        }
        #pragma unroll
        for (int i=0;i<32;i++){
            const float xv = a2[i];
            const float* wr = W2e + i*16;
            #pragma unroll
            for (int o=0;o<16;o++) sc[o] = fmaf(xv, wr[o], sc[o]);
        }

        // exact first-occurrence argmax, per lane (reference semantics)
        float best = sc[0]; int bi = 0;
        #pragma unroll
        for (int k=1;k<16;k++) if (sc[k] > best){ best = sc[k]; bi = k; }

        if (lane < m){
            if (S3){
                int v = (int)raw12[hw]*8 + bi - 4;
                v = v < 0 ? 0 : (v > 511 ? 511 : v);
                out[hw] = v;
            } else {
                const int raw = c*8 + bi - 4;   // c<8 -> fits i8
                raw12[hw] = (signed char)raw;
                cls2[hw]  = (unsigned char)(raw < 0 ? 0 : (raw > 63 ? 63 : raw));
            }
        }
    }
}

extern "C" void kernel_launch(void* const* d_in, const int* in_sizes, int n_in,
                              void* d_out, int out_size, void* d_ws, size_t ws_size,
                              hipStream_t stream) {
    const float* X    = (const float*)d_in[0];
    const float* w1_0 = (const float*)d_in[1];
    const float* b1_0 = (const float*)d_in[2];
    const float* w1_1 = (const float*)d_in[3];
    const float* b1_1 = (const float*)d_in[4];
    const float* w1_2 = (const float*)d_in[5];
    const float* b1_2 = (const float*)d_in[6];
    const float* w2_0 = (const float*)d_in[7];
    const float* b2_0 = (const float*)d_in[8];
    const float* w2_1 = (const float*)d_in[9];
    const float* b2_1 = (const float*)d_in[10];
    const float* w2_2 = (const float*)d_in[11];
    const float* b2_2 = (const float*)d_in[12];
    const float* w3_0 = (const float*)d_in[13];
    const float* b3_0 = (const float*)d_in[14];
    const float* w3_1 = (const float*)d_in[15];
    const float* b3_1 = (const float*)d_in[16];
    const float* w3_2 = (const float*)d_in[17];
    const float* b3_2 = (const float*)d_in[18];
    int* out = (int*)d_out;

    unsigned char* inds1 = (unsigned char*)d_ws;
    unsigned char* cls2  = inds1 + HW_;
    signed char*   raw12 = (signed char*)(cls2 + HW_);

    k1_stage1<<<H_*2, 384, 0, stream>>>(X, w1_0, b1_0, w1_1, b1_1, w1_2, b1_2, inds1);
    condmul_swave<8,  false><<<H_, 512, 0, stream>>>(X, w2_0, b2_0, w2_1, b2_1, w2_2, b2_2,
                                                     inds1, raw12, cls2, out);
    condmul_swave<64, true ><<<H_, 512, 0, stream>>>(X, w3_0, b3_0, w3_1, b3_1, w3_2, b3_2,
                                                     cls2, raw12, cls2, out);
}